// Round 8
// baseline (88.655 us; speedup 1.0000x reference)
//
#include <hip/hip_runtime.h>

// NonLinearConv2d: ik[b,oc,h,w] = ALPHA * sum_{cin,kh,kw} [ sp2((v-t)/D) - sp2((v-t-VD)/D) ]
//   v = clip(x,0,9) zero-padded patch, t = clip(theta,1,8), sp2(a)=log1p(exp(a))^2
//
// Round 8: 2-node pipeline with CHEAP fused prologue (ballot compaction).
//  * node 1: vmax_part -> 64 plain-stored partial maxima (no memset, no atomics).
//  * node 2: nlfused. Each wave builds the 2 oc-lists IT will consume via
//    wave-level ballot/prefix compaction (deterministic, no atomics, no
//    cross-wave sharing -> no barrier needed for the lists; r6's 21us mistake
//    was 8-oc branchy atomic compaction consumed block-wide).
//  * u = exp((v-t)/D) = Ev*Et; Ev staged in LDS tile; Et in the LDS lists.
//    Hot loop: zero global reads, zero exp.
//      t >= vmax+0.45  : dropped  (err <= ALPHA*288*0.93*e^-12 ~ 9.2e-7; passed r6)
//      t >= vmax+0.131 : u<=0.175 quartic series f=u^2(C2-C3u+C4u^2)
//      else            : exact, 2x __logf
//  * LDS: 17408(Ev) + 18432(lists) = 35840 -> 4 blocks/CU, 16 waves/CU.
//  * r3 lesson: keep list reads wave-uniform; r4 lesson: never re-stage
//    atomically-permuted lists across kernels; r6 lesson: no redundant
//    block-wide list building; r5/r7 lesson: don't break scalarization.

#define B_    16
#define CIN_  32
#define H_    32
#define W_    32
#define OC_   64
#define CKK_  288

#define INV_D  13.333333333333334f
#define ALPHA_ 0.0005625f
#define KC     0.26359713811572677f   // e^{-4/3}
#define C2_    0.93051654475128f      // 1 - K^2
#define C3_    0.98168436111127f      // 1 - K^3
#define C4_    0.91224137800000f      // (11/12)(1 - K^4)

#define CUT_DROP 0.45f
#define CUT_A    0.131f

#define WS_NEEDED 256                 // 64 float partials

__device__ __forceinline__ float clipf(float v, float lo, float hi) {
    return fminf(fmaxf(v, lo), hi);
}

__global__ void vmax_part(const float4* __restrict__ x4, float* __restrict__ part, int n4) {
    float m = 0.0f;
    for (int i = blockIdx.x * blockDim.x + threadIdx.x; i < n4; i += gridDim.x * blockDim.x) {
        float4 v = x4[i];
        m = fmaxf(fmaxf(m, clipf(v.x, 0.0f, 9.0f)),
                  fmaxf(clipf(v.y, 0.0f, 9.0f),
                        fmaxf(clipf(v.z, 0.0f, 9.0f), clipf(v.w, 0.0f, 9.0f))));
    }
    #pragma unroll
    for (int off = 32; off > 0; off >>= 1)
        m = fmaxf(m, __shfl_down(m, off, 64));
    __shared__ float sm[4];
    int lane = threadIdx.x & 63, wid = threadIdx.x >> 6;
    if (lane == 0) sm[wid] = m;
    __syncthreads();
    if (threadIdx.x == 0)
        part[blockIdx.x] = fmaxf(fmaxf(sm[0], sm[1]), fmaxf(sm[2], sm[3]));
}

__device__ __forceinline__ float reduce_vmax64(const float* __restrict__ part, int lane) {
    float m = part[lane];                       // 64 floats, L2 broadcast
    #pragma unroll
    for (int off = 32; off > 0; off >>= 1)
        m = fmaxf(m, __shfl_down(m, off, 64));
    return __shfl(m, 0, 64);
}

__launch_bounds__(256, 4)
__global__ void nlfused(const float* __restrict__ x,
                        const float* __restrict__ theta,
                        const float* __restrict__ part,
                        float* __restrict__ out) {
    __shared__ float sx[CIN_ * 136];    // Ev tile: 32cin x 4row x 34col = 17408 B
    __shared__ int2  sL[8 * CKK_];      // 8 oc slots: A bottom-up, B top-down

    const int blk = blockIdx.x;         // b*128 + rp*8 + ocg
    const int ocg = blk & 7;
    const int rp  = (blk >> 3) & 15;
    const int b   = blk >> 7;

    const int tid  = threadIdx.x;
    const int lane = tid & 63;
    const int wv   = tid >> 6;          // wave -> 2 ocs

    const float vmax = reduce_vmax64(part, lane);
    const float cutB = vmax + CUT_DROP;
    const float cutA = vmax + CUT_A;

    // ---- issue all 10 theta loads up-front (one latency window) ----
    float tv[2][5];
    #pragma unroll
    for (int k = 0; k < 2; ++k) {
        const int oc = ocg * 8 + wv * 2 + k;
        #pragma unroll
        for (int c = 0; c < 5; ++c) {
            const int j = c * 64 + lane;
            tv[k][c] = (j < CKK_) ? theta[oc * CKK_ + j] : 1e9f;
        }
    }

    // ---- per-wave ballot compaction: build the 2 lists this wave consumes ----
    const unsigned long long lmlt = (1ULL << lane) - 1;   // lanes below me
    int caL[2], cbL[2];
    #pragma unroll
    for (int k = 0; k < 2; ++k) {
        const int slot = (wv * 2 + k) * CKK_;
        int cA = 0, cB = 0;
        #pragma unroll
        for (int c = 0; c < 5; ++c) {
            const int j = c * 64 + lane;
            const float t = clipf(tv[k][c], 1.0f, 8.0f);  // 1e9 stays >= cutB
            const bool inA = (t < cutA);
            const bool inB = (!inA) && (t < cutB);
            const unsigned long long mA = __ballot(inA);
            const unsigned long long mB = __ballot(inB);
            const int cin = j / 9;
            const int r   = j - cin * 9;
            int2 e;
            e.x = cin * 136 + (r / 3) * 34 + (r % 3);     // Ev-tile offset
            e.y = __float_as_int(__expf(-t * INV_D));     // Et
            if (inA) sL[slot + cA + __popcll(mA & lmlt)] = e;
            if (inB) sL[slot + (CKK_ - 1) - (cB + __popcll(mB & lmlt))] = e;
            cA += (int)__popcll(mA);
            cB += (int)__popcll(mB);
        }
        caL[k] = cA; cbL[k] = cB;       // wave-uniform (from ballot popcounts)
    }

    // ---- stage Ev = exp(clip(x)/D); padded cells -> exp(0)=1 ----
    for (int idx = tid; idx < CIN_ * 136; idx += 256) {
        int cin = idx / 136;
        int rem = idx - cin * 136;
        int rr  = rem / 34;
        int cc  = rem - rr * 34;
        int ir  = rp * 2 - 1 + rr;
        int ic  = cc - 1;
        float ev = 1.0f;
        if ((unsigned)ir < (unsigned)H_ && (unsigned)ic < (unsigned)W_)
            ev = __expf(clipf(x[((b * CIN_ + cin) * H_ + ir) * W_ + ic], 0.0f, 9.0f) * INV_D);
        sx[idx] = ev;
    }
    __syncthreads();                    // sx ready (sL needs no barrier: builder==consumer)

    const int rl    = lane >> 5;        // row within the pair
    const int w     = lane & 31;
    const int myoff = rl * 34 + w;
    const int row   = rp * 2 + rl;

    #pragma unroll
    for (int k = 0; k < 2; ++k) {
        const int oc   = ocg * 8 + wv * 2 + k;
        const int base = (wv * 2 + k) * CKK_;
        const int ca   = caL[k];
        const int cb   = cbL[k];

        float accA = 0.0f, accB = 0.0f;

        #pragma unroll 2
        for (int i = 0; i < ca; ++i) {           // exact tier: 2 logs
            const int2 e = sL[base + i];         // wave-uniform -> broadcast
            const float u  = sx[e.x + myoff] * __int_as_float(e.y);
            const float l1 = __logf(1.0f + u);
            const float l2 = __logf(fmaf(u, KC, 1.0f));
            accA += (l1 - l2) * (l1 + l2);
        }
        #pragma unroll 4
        for (int i = 0; i < cb; ++i) {           // series tier: no transcendentals
            const int2 e = sL[base + (CKK_ - 1) - i];
            const float u = sx[e.x + myoff] * __int_as_float(e.y);
            float p = fmaf(u, C4_, -C3_);
            p = fmaf(u, p, C2_);
            accB = fmaf(u * u, p, accB);
        }

        out[((b * OC_ + oc) * H_ + row) * W_ + w] = ALPHA_ * (accA + accB);
    }
}

// ---------- fallback (ws too small): self-contained, conservative vmax ----------
__launch_bounds__(256)
__global__ void nlconv_fallback(const float* __restrict__ x,
                                const float* __restrict__ theta,
                                float* __restrict__ out) {
    __shared__ int   s_base[CKK_];
    __shared__ float s_t[CKK_];
    __shared__ int   s_d[CKK_];
    __shared__ int   s_cnt;
    const int blk = blockIdx.x;
    const int b  = blk >> 6;
    const int oc = blk & 63;
    if (threadIdx.x == 0) s_cnt = 0;
    __syncthreads();
    const float cutoff = 9.6f;          // vmax<=9 conservative: keep everything
    for (int j = threadIdx.x; j < CKK_; j += blockDim.x) {
        float t = clipf(theta[oc * CKK_ + j], 1.0f, 8.0f);
        if (t < cutoff) {
            int i = atomicAdd(&s_cnt, 1);
            int cin = j / 9;
            int r   = j - cin * 9;
            s_base[i] = cin * (H_ * W_);
            s_t[i]    = t;
            s_d[i]    = (r / 3) | ((r % 3) << 8);
        }
    }
    __syncthreads();
    const int cnt = s_cnt;
    const float* xb = x + b * (CIN_ * H_ * W_);
    const int w  = threadIdx.x & 31;
    const int h0 = threadIdx.x >> 5;
    float acc[4] = {0.f, 0.f, 0.f, 0.f};
    for (int i = 0; i < cnt; ++i) {
        const float t    = s_t[i];
        const int   base = s_base[i];
        const int   d    = s_d[i];
        const int   rdh  = (d & 0xff) - 1;
        const int   rdw  = (d >> 8) - 1;
        const int  col   = w + rdw;
        const bool colok = (unsigned)col < (unsigned)W_;
        const int  ccol  = min(max(col, 0), W_ - 1);
        const float tq   = t * INV_D;
        #pragma unroll
        for (int k = 0; k < 4; ++k) {
            const int  row   = h0 + k * 8 + rdh;
            const bool rowok = (unsigned)row < (unsigned)H_;
            const int  crow  = min(max(row, 0), H_ - 1);
            const float xv   = xb[base + crow * W_ + ccol];
            const float v    = (rowok && colok) ? clipf(xv, 0.0f, 9.0f) : 0.0f;
            const float arg  = fmaf(v, INV_D, -tq);
            const float e1   = __expf(arg);
            const float e2   = e1 * KC;
            const float l1   = __logf(1.0f + e1);
            const float l2   = __logf(1.0f + e2);
            acc[k] += (l1 - l2) * (l1 + l2);
        }
    }
    float* ob = out + (b * OC_ + oc) * (H_ * W_);
    #pragma unroll
    for (int k = 0; k < 4; ++k)
        ob[(h0 + k * 8) * W_ + w] = ALPHA_ * acc[k];
}

extern "C" void kernel_launch(void* const* d_in, const int* in_sizes, int n_in,
                              void* d_out, int out_size, void* d_ws, size_t ws_size,
                              hipStream_t stream) {
    const float* x     = (const float*)d_in[0];
    const float* theta = (const float*)d_in[1];
    float* out  = (float*)d_out;

    if (ws_size >= (size_t)WS_NEEDED) {
        float* part = (float*)d_ws;     // all 64 slots plain-stored each call
        const int n4 = (B_ * CIN_ * H_ * W_) / 4;
        vmax_part<<<64, 256, 0, stream>>>((const float4*)x, part, n4);
        nlfused<<<B_ * 16 * 8, 256, 0, stream>>>(x, theta, part, out);
    } else {
        nlconv_fallback<<<B_ * OC_, 256, 0, stream>>>(x, theta, out);
    }
}